// Round 3
// baseline (1712.303 us; speedup 1.0000x reference)
//
#include <hip/hip_runtime.h>
#include <math.h>

#define Hh 160
#define Ww 160
#define Cc 128
#define HW 25600
#define NPIX 102400   // N*H*W, N=4

typedef __attribute__((ext_vector_type(8))) short short8;
typedef __attribute__((ext_vector_type(4))) float f32x4;
typedef __attribute__((ext_vector_type(4))) unsigned int u32x4;

__device__ __forceinline__ unsigned short f2bf(float f) {
    unsigned int u = __float_as_uint(f);
    unsigned int r = (u + 0x7FFFu + ((u >> 16) & 1u)) >> 16;
    return (unsigned short)r;
}

// ws byte layout (all 16B aligned)
#define WS_OFFS 0u                 // 102400*18*4  = 7372800
#define WS_WA   7372800u           // 128*1152*2   = 294912  (bf16 [o][k*128+c])
#define WS_GSUM 7667712u           // 128*4 = 512
#define WS_GSQ  7668224u           // 128*4 = 512
#define WS_RAW  7668736u           // 4*128*25600*4 = 52428800
#define WS_S    60097536u          // P*1152*2 bf16 [px][k*128+c]

// --------------------------------------------------------------------------
// Kernel W: w_dcn [o][c][k] -> wA bf16 [o][k*128+c]
__global__ void wtrans_kernel(const float* __restrict__ w_dcn,
                              unsigned short* __restrict__ wA) {
    int idx = blockIdx.x * 256 + threadIdx.x;   // 128*1152 = 147456
    if (idx >= 128 * 1152) return;
    int o = idx / 1152;
    int rem = idx - o * 1152;
    int k = rem >> 7;
    int c = rem & 127;
    wA[idx] = f2bf(w_dcn[(o * 128 + c) * 9 + k]);
}

// --------------------------------------------------------------------------
// Kernel A: fused tm/tr 3x3 convs -> per-pixel sampling coords (py,px) x 9
__global__ void __launch_bounds__(256) offs_kernel(
    const float* __restrict__ x, const float* __restrict__ w_tm,
    const float* __restrict__ b_tm, const float* __restrict__ w_tr,
    const float* __restrict__ b_tr, float* __restrict__ offs) {
    __shared__ float wt[128 * 9 * 8];
    int t = threadIdx.x;
    for (int idx = t; idx < 6912; idx += 256) {
        int j = idx % 6;
        int rest = idx / 6;
        int tap = rest % 9;
        int c = rest / 9;
        float v = (j < 4) ? w_tm[(j * 128 + c) * 9 + tap]
                          : w_tr[((j - 4) * 128 + c) * 9 + tap];
        wt[rest * 8 + j] = v;
    }
    __syncthreads();
    int p = blockIdx.x * 256 + t;
    int n = p / HW;
    int hw = p - n * HW;
    int h = hw / Ww;
    int w = hw - h * Ww;
    int addr[9];
    float msk[9];
#pragma unroll
    for (int tap = 0; tap < 9; ++tap) {
        int dy = tap / 3 - 1, dx = tap % 3 - 1;
        int yy = h + dy, xx = w + dx;
        bool v = (yy >= 0) && (yy < Hh) && (xx >= 0) && (xx < Ww);
        addr[tap] = v ? yy * Ww + xx : 0;
        msk[tap] = v ? 1.f : 0.f;
    }
    float a0 = 0, a1 = 0, a2 = 0, a3 = 0, a4 = 0, a5 = 0;
    const float* xn = x + n * Cc * HW;
    for (int c = 0; c < Cc; ++c) {
        const float* xc = xn + c * HW;
#pragma unroll
        for (int tap = 0; tap < 9; ++tap) {
            float v = msk[tap] * xc[addr[tap]];
            const float* wp = &wt[(c * 9 + tap) * 8];
            float4 w4 = *(const float4*)wp;
            float2 w2 = *(const float2*)(wp + 4);
            a0 += v * w4.x; a1 += v * w4.y; a2 += v * w4.z; a3 += v * w4.w;
            a4 += v * w2.x; a5 += v * w2.y;
        }
    }
    a0 += b_tm[0]; a1 += b_tm[1]; a2 += b_tm[2]; a3 += b_tm[3];
    a4 += b_tr[0]; a5 += b_tr[1];
    float* op = offs + (size_t)p * 18;
#pragma unroll
    for (int k = 0; k < 9; ++k) {
        float r0 = (float)(k / 3) - 1.f;
        float r1 = (float)(k % 3) - 1.f;
        op[k * 2 + 0] = (float)h + a0 * r0 + a1 * r1 + a4;
        op[k * 2 + 1] = (float)w + a2 * r0 + a3 * r1 + a5;
    }
}

// --------------------------------------------------------------------------
// Kernel S: bilinear sampler. Block = 32 px; thread t: pl=t&31, cq=t>>5
// handles 16 channels. No LDS, no syncthreads -> TLP hides gather latency.
// Writes S[px_local][k*128+c] bf16 (nontemporal, 32B per thread per k).
__global__ void __launch_bounds__(256) sample_kernel(
    const float* __restrict__ x, const float* __restrict__ offs,
    unsigned short* __restrict__ S, int px_base) {
    int t = threadIdx.x;
    int pl = t & 31;
    int cq = t >> 5;
    int row = blockIdx.x * 32 + pl;         // local S row
    int p = px_base + row;                  // global pixel
    int n = p / HW;
    const float* xn = x + (size_t)n * Cc * HW;
    const float* op = offs + (size_t)p * 18;
    unsigned short* Srow = S + (size_t)row * 1152 + cq * 16;

    for (int k = 0; k < 9; ++k) {
        float py = op[k * 2 + 0];
        float px = op[k * 2 + 1];
        float y0f = floorf(py), x0f = floorf(px);
        float fy = py - y0f, fx = px - x0f;
        int y0 = (int)y0f, xi0 = (int)x0f;
        int y1 = y0 + 1, xi1 = xi0 + 1;
        float w00 = (1.f - fy) * (1.f - fx), w01 = (1.f - fy) * fx;
        float w10 = fy * (1.f - fx), w11 = fy * fx;
        bool vy0 = (unsigned)y0 < (unsigned)Hh, vy1 = (unsigned)y1 < (unsigned)Hh;
        bool vx0 = (unsigned)xi0 < (unsigned)Ww, vx1 = (unsigned)xi1 < (unsigned)Ww;
        w00 = (vy0 && vx0) ? w00 : 0.f;
        w01 = (vy0 && vx1) ? w01 : 0.f;
        w10 = (vy1 && vx0) ? w10 : 0.f;
        w11 = (vy1 && vx1) ? w11 : 0.f;
        int cy0 = vy0 ? y0 : 0, cy1 = vy1 ? y1 : 0;
        int cx0 = vx0 ? xi0 : 0, cx1 = vx1 ? xi1 : 0;
        int o00 = cy0 * Ww + cx0, o01 = cy0 * Ww + cx1;
        int o10 = cy1 * Ww + cx0, o11 = cy1 * Ww + cx1;

        unsigned int pk[8];
#pragma unroll
        for (int i = 0; i < 16; ++i) {
            const float* xc = xn + (cq * 16 + i) * HW;
            float s = w00 * xc[o00] + w01 * xc[o01] +
                      w10 * xc[o10] + w11 * xc[o11];
            unsigned int u = (unsigned int)f2bf(s);
            if (i & 1) pk[i >> 1] |= u << 16;
            else       pk[i >> 1] = u;
        }
        u32x4 lo = {pk[0], pk[1], pk[2], pk[3]};
        u32x4 hi = {pk[4], pk[5], pk[6], pk[7]};
        u32x4* dst = (u32x4*)(Srow + k * 128);
        __builtin_nontemporal_store(lo, dst);
        __builtin_nontemporal_store(hi, dst + 1);
    }
}

// --------------------------------------------------------------------------
// Kernel G: bf16 MFMA GEMM. D[o=128][px=128] per block, K = 1152.
// A = wA[o][kc] bf16, B = S[px][kc] bf16. 4 waves, each 64x64 (4x4 MFMA tiles).
// Epilogue: raw fp32 + GroupNorm sum/sumsq via shfl-reduce + global atomics.
__global__ void __launch_bounds__(256) gemm_kernel(
    const unsigned short* __restrict__ S, const unsigned short* __restrict__ wA,
    float* __restrict__ raw, float* __restrict__ gsum, float* __restrict__ gsq,
    int px_base) {
    // LDS tiles: 128 rows x 64B of bf16 (32 kc), row stride 80B (pad 16B)
    __shared__ __align__(16) char At[128 * 80];
    __shared__ __align__(16) char Bt[128 * 80];
    int t = threadIdx.x;
    int lane = t & 63;
    int wid = t >> 6;
    int wm = wid >> 1, wn = wid & 1;
    int quad = lane >> 4, l15 = lane & 15;

    int px0 = px_base + blockIdx.x * 128;
    int n = px0 / HW;
    int hw0 = px0 - n * HW;
    const char* Ag = (const char*)wA;                       // row = o, 2304B
    const char* Bg = (const char*)(S + (size_t)blockIdx.x * 128 * 1152);

    f32x4 acc[4][4];
#pragma unroll
    for (int i = 0; i < 4; ++i)
#pragma unroll
        for (int j = 0; j < 4; ++j) acc[i][j] = (f32x4)0.f;

    int r0 = t >> 2;
    int cb = (t & 3) * 16;     // byte col within 64B row-chunk

    for (int s = 0; s < 36; ++s) {
        u32x4 av0 = *(const u32x4*)(Ag + (size_t)r0 * 2304 + s * 64 + cb);
        u32x4 av1 = *(const u32x4*)(Ag + (size_t)(r0 + 64) * 2304 + s * 64 + cb);
        u32x4 bv0 = *(const u32x4*)(Bg + (size_t)r0 * 2304 + s * 64 + cb);
        u32x4 bv1 = *(const u32x4*)(Bg + (size_t)(r0 + 64) * 2304 + s * 64 + cb);
        __syncthreads();
        *(u32x4*)&At[r0 * 80 + cb] = av0;
        *(u32x4*)&At[(r0 + 64) * 80 + cb] = av1;
        *(u32x4*)&Bt[r0 * 80 + cb] = bv0;
        *(u32x4*)&Bt[(r0 + 64) * 80 + cb] = bv1;
        __syncthreads();
        short8 a[4], b[4];
#pragma unroll
        for (int i = 0; i < 4; ++i)
            a[i] = *(const short8*)&At[(wm * 64 + i * 16 + l15) * 80 + quad * 16];
#pragma unroll
        for (int j = 0; j < 4; ++j)
            b[j] = *(const short8*)&Bt[(wn * 64 + j * 16 + l15) * 80 + quad * 16];
#pragma unroll
        for (int i = 0; i < 4; ++i)
#pragma unroll
            for (int j = 0; j < 4; ++j)
                acc[i][j] = __builtin_amdgcn_mfma_f32_16x16x32_bf16(
                    a[i], b[j], acc[i][j], 0, 0, 0);
    }

    // epilogue: raw out (D[m=o][n=px]) + group sums
    size_t rbase = ((size_t)n * Cc) * HW + hw0;
#pragma unroll
    for (int i = 0; i < 4; ++i) {
        float s_i = 0.f, q_i = 0.f;
#pragma unroll
        for (int j = 0; j < 4; ++j) {
            int pxl = wn * 64 + j * 16 + l15;
#pragma unroll
            for (int r = 0; r < 4; ++r) {
                int o = wm * 64 + i * 16 + quad * 4 + r;
                float v = acc[i][j][r];
                raw[rbase + (size_t)o * HW + pxl] = v;
                s_i += v;
                q_i += v * v;
            }
        }
#pragma unroll
        for (int m = 1; m < 16; m <<= 1) {
            s_i += __shfl_xor(s_i, m);
            q_i += __shfl_xor(q_i, m);
        }
        if (l15 == 0) {
            int g = wm * 16 + i * 4 + quad;     // = o>>2
            atomicAdd(&gsum[n * 32 + g], s_i);
            atomicAdd(&gsq[n * 32 + g], q_i);
        }
    }
}

// --------------------------------------------------------------------------
// Kernel C: GroupNorm finalize + residual + ReLU (float4)
__global__ void __launch_bounds__(256) finish_kernel(
    const float* __restrict__ raw, const float* __restrict__ x,
    const float* __restrict__ gsum, const float* __restrict__ gsq,
    const float* __restrict__ gamma, const float* __restrict__ beta,
    float* __restrict__ out) {
    int i = blockIdx.x * 256 + threadIdx.x;
    int e = i * 4;
    int n = e / (Cc * HW);
    int rem = e - n * (Cc * HW);
    int c = rem / HW;
    int g = c >> 2;
    const float inv = 1.f / 102400.f;
    float mu = gsum[n * 32 + g] * inv;
    float var = gsq[n * 32 + g] * inv - mu * mu;
    float rs = rsqrtf(var + 1e-5f);
    float sc = gamma[c] * rs;
    float sh = beta[c] - mu * sc;
    float4 v = *(const float4*)&raw[e];
    float4 xv = *(const float4*)&x[e];
    float4 r;
    r.x = fmaxf(v.x * sc + sh + xv.x, 0.f);
    r.y = fmaxf(v.y * sc + sh + xv.y, 0.f);
    r.z = fmaxf(v.z * sc + sh + xv.z, 0.f);
    r.w = fmaxf(v.w * sc + sh + xv.w, 0.f);
    *(float4*)&out[e] = r;
}

// --------------------------------------------------------------------------
extern "C" void kernel_launch(void* const* d_in, const int* in_sizes, int n_in,
                              void* d_out, int out_size, void* d_ws, size_t ws_size,
                              hipStream_t stream) {
    const float* x      = (const float*)d_in[0];
    const float* w_tm   = (const float*)d_in[1];
    const float* b_tm   = (const float*)d_in[2];
    const float* w_tr   = (const float*)d_in[3];
    const float* b_tr   = (const float*)d_in[4];
    const float* w_dcn  = (const float*)d_in[5];
    const float* gamma  = (const float*)d_in[6];
    const float* beta   = (const float*)d_in[7];
    char* ws = (char*)d_ws;
    float*          offs = (float*)(ws + WS_OFFS);
    unsigned short* wA   = (unsigned short*)(ws + WS_WA);
    float*          gsum = (float*)(ws + WS_GSUM);
    float*          gsq  = (float*)(ws + WS_GSQ);
    float*          raw  = (float*)(ws + WS_RAW);
    unsigned short* S    = (unsigned short*)(ws + WS_S);
    float* out = (float*)d_out;

    // pick the largest pixel-chunk whose S fits the workspace
    int P = 6400;
    if      (WS_S + 102400ull * 2304 <= ws_size) P = 102400;
    else if (WS_S +  25600ull * 2304 <= ws_size) P = 25600;
    else if (WS_S +  12800ull * 2304 <= ws_size) P = 12800;

    (void)hipMemsetAsync(gsum, 0, 1024, stream);   // gsum + gsq
    wtrans_kernel<<<576, 256, 0, stream>>>(w_dcn, wA);
    offs_kernel<<<400, 256, 0, stream>>>(x, w_tm, b_tm, w_tr, b_tr, offs);
    for (int base = 0; base < NPIX; base += P) {
        sample_kernel<<<P / 32, 256, 0, stream>>>(x, offs, S, base);
        gemm_kernel<<<P / 128, 256, 0, stream>>>(S, wA, raw, gsum, gsq, base);
    }
    finish_kernel<<<12800, 256, 0, stream>>>(raw, x, gsum, gsq, gamma, beta, out);
}

// Round 4
// 563.506 us; speedup vs baseline: 3.0387x; 3.0387x over previous
//
#include <hip/hip_runtime.h>
#include <math.h>

#define Hh 160
#define Ww 160
#define Cc 128
#define HW 25600
#define NPIX 102400   // N*H*W, N=4

typedef __attribute__((ext_vector_type(8))) short short8;
typedef __attribute__((ext_vector_type(4))) float f32x4;
typedef __attribute__((ext_vector_type(4))) unsigned int u32x4;

__device__ __forceinline__ unsigned short f2bf(float f) {
    unsigned int u = __float_as_uint(f);
    unsigned int r = (u + 0x7FFFu + ((u >> 16) & 1u)) >> 16;
    return (unsigned short)r;
}
__device__ __forceinline__ float bflo(unsigned int u) {
    return __uint_as_float(u << 16);
}
__device__ __forceinline__ float bfhi(unsigned int u) {
    return __uint_as_float(u & 0xffff0000u);
}

// ws byte layout (all 16B aligned)
#define WS_OFFS 0u             // 102400*18*4 = 7372800
#define WS_WA   7372800u       // 128*1152*2  = 294912
#define WS_GSUM 7667712u       // 512
#define WS_GSQ  7668224u       // 512
#define WS_XT   7668736u       // 102400*128*2 = 26214400 (bf16 NHWC)
#define WS_RAW  33883136u      // 4*128*25600*4 = 52428800
#define WS_S    86311936u      // P*1152*2 bf16 [px][k*128+c]

// --------------------------------------------------------------------------
// Kernel W: w_dcn [o][c][k] -> wA bf16 [o][k*128+c]
__global__ void wtrans_kernel(const float* __restrict__ w_dcn,
                              unsigned short* __restrict__ wA) {
    int idx = blockIdx.x * 256 + threadIdx.x;
    if (idx >= 128 * 1152) return;
    int o = idx / 1152;
    int rem = idx - o * 1152;
    int k = rem >> 7;
    int c = rem & 127;
    wA[idx] = f2bf(w_dcn[(o * 128 + c) * 9 + k]);
}

// --------------------------------------------------------------------------
// Kernel X: NCHW fp32 -> NHWC bf16 transpose via LDS tile
__global__ void __launch_bounds__(256) xpose_kernel(
    const float* __restrict__ x, unsigned short* __restrict__ xT) {
    __shared__ float L[128 * 65];       // +1 pad breaks bank conflicts
    int b = blockIdx.x;                 // 4 n * 400 tiles
    int n = b / 400;
    int px0 = (b - n * 400) * 64;
    int t = threadIdx.x;
    const float* xn = x + (size_t)n * Cc * HW + px0;
#pragma unroll
    for (int i = 0; i < 32; ++i) {
        int idx = i * 256 + t;
        int ch = idx >> 6;
        int pxl = idx & 63;
        L[ch * 65 + pxl] = xn[(size_t)ch * HW + pxl];
    }
    __syncthreads();
    unsigned short* dst = xT + ((size_t)n * HW + px0) * 128;
#pragma unroll
    for (int j = 0; j < 16; ++j) {
        int idx = j * 256 + t;
        int pxl = idx >> 6;
        int cp = idx & 63;              // channel pair
        unsigned int u = (unsigned)f2bf(L[(2 * cp) * 65 + pxl]) |
                         ((unsigned)f2bf(L[(2 * cp + 1) * 65 + pxl]) << 16);
        *(unsigned int*)(dst + (size_t)pxl * 128 + cp * 2) = u;
    }
}

// --------------------------------------------------------------------------
// Kernel A: fused tm/tr 3x3 convs -> per-pixel sampling coords (py,px) x 9
__global__ void __launch_bounds__(256) offs_kernel(
    const float* __restrict__ x, const float* __restrict__ w_tm,
    const float* __restrict__ b_tm, const float* __restrict__ w_tr,
    const float* __restrict__ b_tr, float* __restrict__ offs) {
    __shared__ float wt[128 * 9 * 8];
    int t = threadIdx.x;
    for (int idx = t; idx < 6912; idx += 256) {
        int j = idx % 6;
        int rest = idx / 6;
        int tap = rest % 9;
        int c = rest / 9;
        float v = (j < 4) ? w_tm[(j * 128 + c) * 9 + tap]
                          : w_tr[((j - 4) * 128 + c) * 9 + tap];
        wt[rest * 8 + j] = v;
    }
    __syncthreads();
    int p = blockIdx.x * 256 + t;
    int n = p / HW;
    int hw = p - n * HW;
    int h = hw / Ww;
    int w = hw - h * Ww;
    int addr[9];
    float msk[9];
#pragma unroll
    for (int tap = 0; tap < 9; ++tap) {
        int dy = tap / 3 - 1, dx = tap % 3 - 1;
        int yy = h + dy, xx = w + dx;
        bool v = (yy >= 0) && (yy < Hh) && (xx >= 0) && (xx < Ww);
        addr[tap] = v ? yy * Ww + xx : 0;
        msk[tap] = v ? 1.f : 0.f;
    }
    float a0 = 0, a1 = 0, a2 = 0, a3 = 0, a4 = 0, a5 = 0;
    const float* xn = x + n * Cc * HW;
    for (int c = 0; c < Cc; ++c) {
        const float* xc = xn + c * HW;
#pragma unroll
        for (int tap = 0; tap < 9; ++tap) {
            float v = msk[tap] * xc[addr[tap]];
            const float* wp = &wt[(c * 9 + tap) * 8];
            float4 w4 = *(const float4*)wp;
            float2 w2 = *(const float2*)(wp + 4);
            a0 += v * w4.x; a1 += v * w4.y; a2 += v * w4.z; a3 += v * w4.w;
            a4 += v * w2.x; a5 += v * w2.y;
        }
    }
    a0 += b_tm[0]; a1 += b_tm[1]; a2 += b_tm[2]; a3 += b_tm[3];
    a4 += b_tr[0]; a5 += b_tr[1];
    float* op = offs + (size_t)p * 18;
#pragma unroll
    for (int k = 0; k < 9; ++k) {
        float r0 = (float)(k / 3) - 1.f;
        float r1 = (float)(k % 3) - 1.f;
        op[k * 2 + 0] = (float)h + a0 * r0 + a1 * r1 + a4;
        op[k * 2 + 1] = (float)w + a2 * r0 + a3 * r1 + a5;
    }
}

// --------------------------------------------------------------------------
// Kernel S: bilinear sampler on NHWC bf16 xT. Block = 32 px, thread:
// cq = t&7 (16-ch chunk), pl = t>>3 (px). Corner reads are 32B contiguous,
// 8 adjacent lanes cover a full 256B cell. Regular stores keep S in L3.
__global__ void __launch_bounds__(256) sample_kernel(
    const unsigned short* __restrict__ xT, const float* __restrict__ offs,
    unsigned short* __restrict__ S, int px_base) {
    int t = threadIdx.x;
    int cq = t & 7;
    int pl = t >> 3;
    int row = blockIdx.x * 32 + pl;
    int p = px_base + row;
    int n = p / HW;
    const unsigned short* xb = xT + ((size_t)n * HW) * 128 + cq * 16;
    const float* op = offs + (size_t)p * 18;
    unsigned short* Srow = S + (size_t)row * 1152 + cq * 16;

#pragma unroll
    for (int k = 0; k < 9; ++k) {
        float py = op[2 * k + 0];
        float px = op[2 * k + 1];
        float y0f = floorf(py), x0f = floorf(px);
        float fy = py - y0f, fx = px - x0f;
        int y0 = (int)y0f, xi0 = (int)x0f;
        int y1 = y0 + 1, xi1 = xi0 + 1;
        float w00 = (1.f - fy) * (1.f - fx), w01 = (1.f - fy) * fx;
        float w10 = fy * (1.f - fx), w11 = fy * fx;
        bool vy0 = (unsigned)y0 < (unsigned)Hh, vy1 = (unsigned)y1 < (unsigned)Hh;
        bool vx0 = (unsigned)xi0 < (unsigned)Ww, vx1 = (unsigned)xi1 < (unsigned)Ww;
        w00 = (vy0 && vx0) ? w00 : 0.f;
        w01 = (vy0 && vx1) ? w01 : 0.f;
        w10 = (vy1 && vx0) ? w10 : 0.f;
        w11 = (vy1 && vx1) ? w11 : 0.f;
        int cy0 = vy0 ? y0 : 0, cy1 = vy1 ? y1 : 0;
        int cx0 = vx0 ? xi0 : 0, cx1 = vx1 ? xi1 : 0;
        const u32x4* c00 = (const u32x4*)(xb + (size_t)(cy0 * Ww + cx0) * 128);
        const u32x4* c01 = (const u32x4*)(xb + (size_t)(cy0 * Ww + cx1) * 128);
        const u32x4* c10 = (const u32x4*)(xb + (size_t)(cy1 * Ww + cx0) * 128);
        const u32x4* c11 = (const u32x4*)(xb + (size_t)(cy1 * Ww + cx1) * 128);
        u32x4 A0 = c00[0], A1 = c00[1];
        u32x4 B0 = c01[0], B1 = c01[1];
        u32x4 C0 = c10[0], C1 = c10[1];
        u32x4 D0 = c11[0], D1 = c11[1];
        u32x4 o0, o1;
#pragma unroll
        for (int i = 0; i < 4; ++i) {
            float lo = w00 * bflo(A0[i]) + w01 * bflo(B0[i]) +
                       w10 * bflo(C0[i]) + w11 * bflo(D0[i]);
            float hi = w00 * bfhi(A0[i]) + w01 * bfhi(B0[i]) +
                       w10 * bfhi(C0[i]) + w11 * bfhi(D0[i]);
            o0[i] = (unsigned)f2bf(lo) | ((unsigned)f2bf(hi) << 16);
            float lo1 = w00 * bflo(A1[i]) + w01 * bflo(B1[i]) +
                        w10 * bflo(C1[i]) + w11 * bflo(D1[i]);
            float hi1 = w00 * bfhi(A1[i]) + w01 * bfhi(B1[i]) +
                        w10 * bfhi(C1[i]) + w11 * bfhi(D1[i]);
            o1[i] = (unsigned)f2bf(lo1) | ((unsigned)f2bf(hi1) << 16);
        }
        *(u32x4*)(Srow + k * 128) = o0;
        *(u32x4*)(Srow + k * 128 + 8) = o1;
    }
}

// --------------------------------------------------------------------------
// Kernel G: bf16 MFMA GEMM. D[o=128][px=64] per block, K = 1152.
// 4 waves, each 64o x 32px (4x2 MFMA tiles). 2x grid vs 128-px tiles.
__global__ void __launch_bounds__(256) gemm_kernel(
    const unsigned short* __restrict__ S, const unsigned short* __restrict__ wA,
    float* __restrict__ raw, float* __restrict__ gsum, float* __restrict__ gsq,
    int px_base) {
    __shared__ __align__(16) char At[128 * 80];  // row = o, 64B + 16B pad
    __shared__ __align__(16) char Bt[64 * 80];   // row = px
    int t = threadIdx.x;
    int lane = t & 63;
    int wid = t >> 6;
    int wm = wid & 1, wn = wid >> 1;
    int quad = lane >> 4, l15 = lane & 15;

    int px0 = px_base + blockIdx.x * 64;
    int n = px0 / HW;
    int hw0 = px0 - n * HW;
    const char* Ag = (const char*)wA;                        // 2304 B / row
    const char* Bg = (const char*)(S + (size_t)blockIdx.x * 64 * 1152);

    f32x4 acc[4][2];
#pragma unroll
    for (int i = 0; i < 4; ++i)
#pragma unroll
        for (int j = 0; j < 2; ++j) acc[i][j] = (f32x4)0.f;

    int rA = t >> 1, cA = (t & 1) * 32;
    int rB = t >> 2, cB = (t & 3) * 16;

    for (int s = 0; s < 36; ++s) {
        u32x4 av0 = *(const u32x4*)(Ag + (size_t)rA * 2304 + s * 64 + cA);
        u32x4 av1 = *(const u32x4*)(Ag + (size_t)rA * 2304 + s * 64 + cA + 16);
        u32x4 bv  = *(const u32x4*)(Bg + (size_t)rB * 2304 + s * 64 + cB);
        __syncthreads();
        *(u32x4*)&At[rA * 80 + cA] = av0;
        *(u32x4*)&At[rA * 80 + cA + 16] = av1;
        *(u32x4*)&Bt[rB * 80 + cB] = bv;
        __syncthreads();
        short8 a[4], b[2];
#pragma unroll
        for (int i = 0; i < 4; ++i)
            a[i] = *(const short8*)&At[(wm * 64 + i * 16 + l15) * 80 + quad * 16];
#pragma unroll
        for (int j = 0; j < 2; ++j)
            b[j] = *(const short8*)&Bt[(wn * 32 + j * 16 + l15) * 80 + quad * 16];
#pragma unroll
        for (int i = 0; i < 4; ++i)
#pragma unroll
            for (int j = 0; j < 2; ++j)
                acc[i][j] = __builtin_amdgcn_mfma_f32_16x16x32_bf16(
                    a[i], b[j], acc[i][j], 0, 0, 0);
    }

    size_t rbase = ((size_t)n * Cc) * HW + hw0;
#pragma unroll
    for (int i = 0; i < 4; ++i) {
        float s_i = 0.f, q_i = 0.f;
#pragma unroll
        for (int j = 0; j < 2; ++j) {
            int pxl = wn * 32 + j * 16 + l15;
#pragma unroll
            for (int r = 0; r < 4; ++r) {
                int o = wm * 64 + i * 16 + quad * 4 + r;
                float v = acc[i][j][r];
                raw[rbase + (size_t)o * HW + pxl] = v;
                s_i += v;
                q_i += v * v;
            }
        }
#pragma unroll
        for (int m = 1; m < 16; m <<= 1) {
            s_i += __shfl_xor(s_i, m);
            q_i += __shfl_xor(q_i, m);
        }
        if (l15 == 0) {
            int g = wm * 16 + i * 4 + quad;
            atomicAdd(&gsum[n * 32 + g], s_i);
            atomicAdd(&gsq[n * 32 + g], q_i);
        }
    }
}

// --------------------------------------------------------------------------
// Kernel C: GroupNorm finalize + residual + ReLU (float4)
__global__ void __launch_bounds__(256) finish_kernel(
    const float* __restrict__ raw, const float* __restrict__ x,
    const float* __restrict__ gsum, const float* __restrict__ gsq,
    const float* __restrict__ gamma, const float* __restrict__ beta,
    float* __restrict__ out) {
    int i = blockIdx.x * 256 + threadIdx.x;
    int e = i * 4;
    int n = e / (Cc * HW);
    int rem = e - n * (Cc * HW);
    int c = rem / HW;
    int g = c >> 2;
    const float inv = 1.f / 102400.f;
    float mu = gsum[n * 32 + g] * inv;
    float var = gsq[n * 32 + g] * inv - mu * mu;
    float rs = rsqrtf(var + 1e-5f);
    float sc = gamma[c] * rs;
    float sh = beta[c] - mu * sc;
    float4 v = *(const float4*)&raw[e];
    float4 xv = *(const float4*)&x[e];
    float4 r;
    r.x = fmaxf(v.x * sc + sh + xv.x, 0.f);
    r.y = fmaxf(v.y * sc + sh + xv.y, 0.f);
    r.z = fmaxf(v.z * sc + sh + xv.z, 0.f);
    r.w = fmaxf(v.w * sc + sh + xv.w, 0.f);
    *(float4*)&out[e] = r;
}

// --------------------------------------------------------------------------
extern "C" void kernel_launch(void* const* d_in, const int* in_sizes, int n_in,
                              void* d_out, int out_size, void* d_ws, size_t ws_size,
                              hipStream_t stream) {
    const float* x      = (const float*)d_in[0];
    const float* w_tm   = (const float*)d_in[1];
    const float* b_tm   = (const float*)d_in[2];
    const float* w_tr   = (const float*)d_in[3];
    const float* b_tr   = (const float*)d_in[4];
    const float* w_dcn  = (const float*)d_in[5];
    const float* gamma  = (const float*)d_in[6];
    const float* beta   = (const float*)d_in[7];
    char* ws = (char*)d_ws;
    float*          offs = (float*)(ws + WS_OFFS);
    unsigned short* wA   = (unsigned short*)(ws + WS_WA);
    float*          gsum = (float*)(ws + WS_GSUM);
    float*          gsq  = (float*)(ws + WS_GSQ);
    unsigned short* xT   = (unsigned short*)(ws + WS_XT);
    float*          raw  = (float*)(ws + WS_RAW);
    unsigned short* S    = (unsigned short*)(ws + WS_S);
    float* out = (float*)d_out;

    int P = 6400;
    if      (WS_S + 102400ull * 2304 <= ws_size) P = 102400;
    else if (WS_S +  25600ull * 2304 <= ws_size) P = 25600;
    else if (WS_S +  12800ull * 2304 <= ws_size) P = 12800;

    (void)hipMemsetAsync(gsum, 0, 1024, stream);   // gsum + gsq
    wtrans_kernel<<<576, 256, 0, stream>>>(w_dcn, wA);
    xpose_kernel<<<1600, 256, 0, stream>>>(x, xT);
    offs_kernel<<<400, 256, 0, stream>>>(x, w_tm, b_tm, w_tr, b_tr, offs);
    for (int base = 0; base < NPIX; base += P) {
        sample_kernel<<<P / 32, 256, 0, stream>>>(xT, offs, S, base);
        gemm_kernel<<<P / 64, 256, 0, stream>>>(S, wA, raw, gsum, gsq, base);
    }
    finish_kernel<<<12800, 256, 0, stream>>>(raw, x, gsum, gsq, gamma, beta, out);
}

// Round 5
// 453.669 us; speedup vs baseline: 3.7743x; 1.2421x over previous
//
#include <hip/hip_runtime.h>
#include <math.h>

#define Hh 160
#define Ww 160
#define Cc 128
#define HW 25600
#define NPIX 102400   // N*H*W, N=4

typedef __attribute__((ext_vector_type(8))) short short8;
typedef __attribute__((ext_vector_type(4))) float f32x4;
typedef __attribute__((ext_vector_type(4))) unsigned int u32x4;

__device__ __forceinline__ unsigned short f2bf(float f) {
    unsigned int u = __float_as_uint(f);
    unsigned int r = (u + 0x7FFFu + ((u >> 16) & 1u)) >> 16;
    return (unsigned short)r;
}
__device__ __forceinline__ float bflo(unsigned int u) {
    return __uint_as_float(u << 16);
}
__device__ __forceinline__ float bfhi(unsigned int u) {
    return __uint_as_float(u & 0xffff0000u);
}

// ws byte layout (all 16B aligned)
#define WS_OFFS 0u             // 102400*18*4 = 7372800
#define WS_WA   7372800u       // 9*128*128*2 = 294912  bf16 [k][o][c]
#define WS_GSUM 7667712u       // 512
#define WS_GSQ  7668224u       // 512
#define WS_XT   7668736u       // 102400*128*2 = 26214400 (bf16 NHWC)
#define WS_RAW  33883136u      // 4*128*25600*4 = 52428800

// --------------------------------------------------------------------------
// Kernel W: w_dcn [o][c][k] -> wA bf16 [k][o][c]  (256B rows, A-frag friendly)
__global__ void wtrans_kernel(const float* __restrict__ w_dcn,
                              unsigned short* __restrict__ wA) {
    int idx = blockIdx.x * 256 + threadIdx.x;
    if (idx >= 9 * 128 * 128) return;
    int k = idx >> 14;
    int o = (idx >> 7) & 127;
    int c = idx & 127;
    wA[idx] = f2bf(w_dcn[(o * 128 + c) * 9 + k]);
}

// --------------------------------------------------------------------------
// Kernel X: NCHW fp32 -> NHWC bf16 transpose via LDS tile
__global__ void __launch_bounds__(256) xpose_kernel(
    const float* __restrict__ x, unsigned short* __restrict__ xT) {
    __shared__ float L[128 * 65];
    int b = blockIdx.x;
    int n = b / 400;
    int px0 = (b - n * 400) * 64;
    int t = threadIdx.x;
    const float* xn = x + (size_t)n * Cc * HW + px0;
#pragma unroll
    for (int i = 0; i < 32; ++i) {
        int idx = i * 256 + t;
        int ch = idx >> 6;
        int pxl = idx & 63;
        L[ch * 65 + pxl] = xn[(size_t)ch * HW + pxl];
    }
    __syncthreads();
    unsigned short* dst = xT + ((size_t)n * HW + px0) * 128;
#pragma unroll
    for (int j = 0; j < 16; ++j) {
        int idx = j * 256 + t;
        int pxl = idx >> 6;
        int cp = idx & 63;
        unsigned int u = (unsigned)f2bf(L[(2 * cp) * 65 + pxl]) |
                         ((unsigned)f2bf(L[(2 * cp + 1) * 65 + pxl]) << 16);
        *(unsigned int*)(dst + (size_t)pxl * 128 + cp * 2) = u;
    }
}

// --------------------------------------------------------------------------
// Kernel A: fused tm/tr 3x3 convs -> per-pixel sampling coords (py,px) x 9
__global__ void __launch_bounds__(256) offs_kernel(
    const float* __restrict__ x, const float* __restrict__ w_tm,
    const float* __restrict__ b_tm, const float* __restrict__ w_tr,
    const float* __restrict__ b_tr, float* __restrict__ offs) {
    __shared__ float wt[128 * 9 * 8];
    int t = threadIdx.x;
    for (int idx = t; idx < 6912; idx += 256) {
        int j = idx % 6;
        int rest = idx / 6;
        int tap = rest % 9;
        int c = rest / 9;
        float v = (j < 4) ? w_tm[(j * 128 + c) * 9 + tap]
                          : w_tr[((j - 4) * 128 + c) * 9 + tap];
        wt[rest * 8 + j] = v;
    }
    __syncthreads();
    int p = blockIdx.x * 256 + t;
    int n = p / HW;
    int hw = p - n * HW;
    int h = hw / Ww;
    int w = hw - h * Ww;
    int addr[9];
    float msk[9];
#pragma unroll
    for (int tap = 0; tap < 9; ++tap) {
        int dy = tap / 3 - 1, dx = tap % 3 - 1;
        int yy = h + dy, xx = w + dx;
        bool v = (yy >= 0) && (yy < Hh) && (xx >= 0) && (xx < Ww);
        addr[tap] = v ? yy * Ww + xx : 0;
        msk[tap] = v ? 1.f : 0.f;
    }
    float a0 = 0, a1 = 0, a2 = 0, a3 = 0, a4 = 0, a5 = 0;
    const float* xn = x + n * Cc * HW;
    for (int c = 0; c < Cc; ++c) {
        const float* xc = xn + c * HW;
#pragma unroll
        for (int tap = 0; tap < 9; ++tap) {
            float v = msk[tap] * xc[addr[tap]];
            const float* wp = &wt[(c * 9 + tap) * 8];
            float4 w4 = *(const float4*)wp;
            float2 w2 = *(const float2*)(wp + 4);
            a0 += v * w4.x; a1 += v * w4.y; a2 += v * w4.z; a3 += v * w4.w;
            a4 += v * w2.x; a5 += v * w2.y;
        }
    }
    a0 += b_tm[0]; a1 += b_tm[1]; a2 += b_tm[2]; a3 += b_tm[3];
    a4 += b_tr[0]; a5 += b_tr[1];
    float* op = offs + (size_t)p * 18;
#pragma unroll
    for (int k = 0; k < 9; ++k) {
        float r0 = (float)(k / 3) - 1.f;
        float r1 = (float)(k % 3) - 1.f;
        op[k * 2 + 0] = (float)h + a0 * r0 + a1 * r1 + a4;
        op[k * 2 + 1] = (float)w + a2 * r0 + a3 * r1 + a5;
    }
}

// --------------------------------------------------------------------------
// Kernel D: FUSED deformable conv. Block = 128 px x 128 o, loop over 9 taps:
//   stage: bilinear-sample B-tile [128px][128c] bf16 into LDS (XOR-swizzled
//          16B units, pad-free, conflict-free for b128 r/w)
//   MFMA:  4 k-steps of 16x16x32, A-frags direct from global wA[k][o][c]
//          (dense 1KB/load pattern, L1/L2-hot), 64 MFMA per wave per tap.
// Epilogue: raw fp32 + GN sum/sumsq via shfl + atomics.
__global__ void __launch_bounds__(256, 3) dcn2_kernel(
    const unsigned short* __restrict__ xT, const float* __restrict__ offs,
    const unsigned short* __restrict__ wA, float* __restrict__ raw,
    float* __restrict__ gsum, float* __restrict__ gsq) {
    __shared__ __align__(16) unsigned short Bt[128 * 128];   // 32 KB
    int t = threadIdx.x;
    int lane = t & 63;
    int wid = t >> 6;
    int wm = wid & 1, wn = wid >> 1;
    int quad = lane >> 4, l15 = lane & 15;

    int px0 = blockIdx.x * 128;            // 800 blocks, no image straddle
    int n = px0 / HW;
    int hw0 = px0 - n * HW;
    int pl = t >> 1;                       // staging pixel 0..127
    int hf = t & 1;                        // staging channel half (64 ch)
    const unsigned short* xb = xT + (size_t)n * HW * 128;
    const float* op = offs + (size_t)(px0 + pl) * 18;
    const char* Ag = (const char*)wA;

    f32x4 acc[4][4];
#pragma unroll
    for (int i = 0; i < 4; ++i)
#pragma unroll
        for (int j = 0; j < 4; ++j) acc[i][j] = (f32x4)0.f;

    for (int k = 0; k < 9; ++k) {
        // ---- my pixel's sampling setup for tap k ----
        float py = op[2 * k + 0];
        float px = op[2 * k + 1];
        float y0f = floorf(py), x0f = floorf(px);
        float fy = py - y0f, fx = px - x0f;
        int y0 = (int)y0f, xi0 = (int)x0f;
        int y1 = y0 + 1, xi1 = xi0 + 1;
        float w00 = (1.f - fy) * (1.f - fx), w01 = (1.f - fy) * fx;
        float w10 = fy * (1.f - fx), w11 = fy * fx;
        bool vy0 = (unsigned)y0 < (unsigned)Hh, vy1 = (unsigned)y1 < (unsigned)Hh;
        bool vx0 = (unsigned)xi0 < (unsigned)Ww, vx1 = (unsigned)xi1 < (unsigned)Ww;
        w00 = (vy0 && vx0) ? w00 : 0.f;
        w01 = (vy0 && vx1) ? w01 : 0.f;
        w10 = (vy1 && vx0) ? w10 : 0.f;
        w11 = (vy1 && vx1) ? w11 : 0.f;
        int cy0 = vy0 ? y0 : 0, cy1 = vy1 ? y1 : 0;
        int cx0 = vx0 ? xi0 : 0, cx1 = vx1 ? xi1 : 0;
        const unsigned short* c00 = xb + (size_t)(cy0 * Ww + cx0) * 128;
        const unsigned short* c01 = xb + (size_t)(cy0 * Ww + cx1) * 128;
        const unsigned short* c10 = xb + (size_t)(cy1 * Ww + cx0) * 128;
        const unsigned short* c11 = xb + (size_t)(cy1 * Ww + cx1) * 128;

        __syncthreads();                   // prev tap's MFMA reads done
#pragma unroll
        for (int uu = 0; uu < 4; ++uu) {
            int ch0 = hf * 64 + uu * 16;   // 16 channels per chunk
            u32x4 A0 = *(const u32x4*)(c00 + ch0);
            u32x4 A1 = *(const u32x4*)(c00 + ch0 + 8);
            u32x4 B0 = *(const u32x4*)(c01 + ch0);
            u32x4 B1 = *(const u32x4*)(c01 + ch0 + 8);
            u32x4 C0 = *(const u32x4*)(c10 + ch0);
            u32x4 C1 = *(const u32x4*)(c10 + ch0 + 8);
            u32x4 D0 = *(const u32x4*)(c11 + ch0);
            u32x4 D1 = *(const u32x4*)(c11 + ch0 + 8);
            u32x4 r0, r1;
#pragma unroll
            for (int e = 0; e < 4; ++e) {
                float lo = w00 * bflo(A0[e]) + w01 * bflo(B0[e]) +
                           w10 * bflo(C0[e]) + w11 * bflo(D0[e]);
                float hi = w00 * bfhi(A0[e]) + w01 * bfhi(B0[e]) +
                           w10 * bfhi(C0[e]) + w11 * bfhi(D0[e]);
                r0[e] = (unsigned)f2bf(lo) | ((unsigned)f2bf(hi) << 16);
                float lo1 = w00 * bflo(A1[e]) + w01 * bflo(B1[e]) +
                            w10 * bflo(C1[e]) + w11 * bflo(D1[e]);
                float hi1 = w00 * bfhi(A1[e]) + w01 * bfhi(B1[e]) +
                            w10 * bfhi(C1[e]) + w11 * bfhi(D1[e]);
                r1[e] = (unsigned)f2bf(lo1) | ((unsigned)f2bf(hi1) << 16);
            }
            int u = ch0 >> 3;              // 16B-unit index (0..15)
            *(u32x4*)&Bt[pl * 128 + (((u    ) ^ (pl & 15)) << 3)] = r0;
            *(u32x4*)&Bt[pl * 128 + (((u + 1) ^ (pl & 15)) << 3)] = r1;
        }
        __syncthreads();

#pragma unroll
        for (int q = 0; q < 4; ++q) {
            short8 a[4], b[4];
#pragma unroll
            for (int i = 0; i < 4; ++i)
                a[i] = *(const short8*)(Ag +
                        ((size_t)(k * 128 + wm * 64 + i * 16 + l15) << 8) +
                        q * 64 + quad * 16);
#pragma unroll
            for (int j = 0; j < 4; ++j) {
                int row = wn * 64 + j * 16 + l15;
                int ur = (q * 4 + quad) ^ (row & 15);
                b[j] = *(const short8*)&Bt[row * 128 + ur * 8];
            }
#pragma unroll
            for (int i = 0; i < 4; ++i)
#pragma unroll
                for (int j = 0; j < 4; ++j)
                    acc[i][j] = __builtin_amdgcn_mfma_f32_16x16x32_bf16(
                        a[i], b[j], acc[i][j], 0, 0, 0);
        }
    }

    // ---- epilogue: raw out (D[m=o][n=px]) + group sums ----
    size_t rbase = ((size_t)n * Cc) * HW + hw0;
#pragma unroll
    for (int i = 0; i < 4; ++i) {
        float s_i = 0.f, q_i = 0.f;
#pragma unroll
        for (int j = 0; j < 4; ++j) {
            int pxl = wn * 64 + j * 16 + l15;
#pragma unroll
            for (int r = 0; r < 4; ++r) {
                int o = wm * 64 + i * 16 + quad * 4 + r;
                float v = acc[i][j][r];
                raw[rbase + (size_t)o * HW + pxl] = v;
                s_i += v;
                q_i += v * v;
            }
        }
#pragma unroll
        for (int m = 1; m < 16; m <<= 1) {
            s_i += __shfl_xor(s_i, m);
            q_i += __shfl_xor(q_i, m);
        }
        if (l15 == 0) {
            int g = wm * 16 + i * 4 + quad;
            atomicAdd(&gsum[n * 32 + g], s_i);
            atomicAdd(&gsq[n * 32 + g], q_i);
        }
    }
}

// --------------------------------------------------------------------------
// Kernel C: GroupNorm finalize + residual + ReLU (float4)
__global__ void __launch_bounds__(256) finish_kernel(
    const float* __restrict__ raw, const float* __restrict__ x,
    const float* __restrict__ gsum, const float* __restrict__ gsq,
    const float* __restrict__ gamma, const float* __restrict__ beta,
    float* __restrict__ out) {
    int i = blockIdx.x * 256 + threadIdx.x;
    int e = i * 4;
    int n = e / (Cc * HW);
    int rem = e - n * (Cc * HW);
    int c = rem / HW;
    int g = c >> 2;
    const float inv = 1.f / 102400.f;
    float mu = gsum[n * 32 + g] * inv;
    float var = gsq[n * 32 + g] * inv - mu * mu;
    float rs = rsqrtf(var + 1e-5f);
    float sc = gamma[c] * rs;
    float sh = beta[c] - mu * sc;
    float4 v = *(const float4*)&raw[e];
    float4 xv = *(const float4*)&x[e];
    float4 r;
    r.x = fmaxf(v.x * sc + sh + xv.x, 0.f);
    r.y = fmaxf(v.y * sc + sh + xv.y, 0.f);
    r.z = fmaxf(v.z * sc + sh + xv.z, 0.f);
    r.w = fmaxf(v.w * sc + sh + xv.w, 0.f);
    *(float4*)&out[e] = r;
}

// --------------------------------------------------------------------------
extern "C" void kernel_launch(void* const* d_in, const int* in_sizes, int n_in,
                              void* d_out, int out_size, void* d_ws, size_t ws_size,
                              hipStream_t stream) {
    const float* x      = (const float*)d_in[0];
    const float* w_tm   = (const float*)d_in[1];
    const float* b_tm   = (const float*)d_in[2];
    const float* w_tr   = (const float*)d_in[3];
    const float* b_tr   = (const float*)d_in[4];
    const float* w_dcn  = (const float*)d_in[5];
    const float* gamma  = (const float*)d_in[6];
    const float* beta   = (const float*)d_in[7];
    char* ws = (char*)d_ws;
    float*          offs = (float*)(ws + WS_OFFS);
    unsigned short* wA   = (unsigned short*)(ws + WS_WA);
    float*          gsum = (float*)(ws + WS_GSUM);
    float*          gsq  = (float*)(ws + WS_GSQ);
    unsigned short* xT   = (unsigned short*)(ws + WS_XT);
    float*          raw  = (float*)(ws + WS_RAW);
    float* out = (float*)d_out;

    (void)hipMemsetAsync(gsum, 0, 1024, stream);   // gsum + gsq
    wtrans_kernel<<<576, 256, 0, stream>>>(w_dcn, wA);
    xpose_kernel<<<1600, 256, 0, stream>>>(x, xT);
    offs_kernel<<<400, 256, 0, stream>>>(x, w_tm, b_tm, w_tr, b_tr, offs);
    dcn2_kernel<<<800, 256, 0, stream>>>(xT, offs, wA, raw, gsum, gsq);
    finish_kernel<<<12800, 256, 0, stream>>>(raw, x, gsum, gsq, gamma, beta, out);
}

// Round 6
// 413.384 us; speedup vs baseline: 4.1422x; 1.0975x over previous
//
#include <hip/hip_runtime.h>
#include <math.h>

#define Hh 160
#define Ww 160
#define Cc 128
#define HW 25600
#define NPIX 102400   // N*H*W, N=4

typedef __attribute__((ext_vector_type(8))) short short8;
typedef __attribute__((ext_vector_type(4))) float f32x4;
typedef __attribute__((ext_vector_type(4))) unsigned int u32x4;

__device__ __forceinline__ unsigned short f2bf(float f) {
    unsigned int u = __float_as_uint(f);
    unsigned int r = (u + 0x7FFFu + ((u >> 16) & 1u)) >> 16;
    return (unsigned short)r;
}
__device__ __forceinline__ float bflo(unsigned int u) {
    return __uint_as_float(u << 16);
}
__device__ __forceinline__ float bfhi(unsigned int u) {
    return __uint_as_float(u & 0xffff0000u);
}

// ws byte layout (all 16B aligned)
#define WS_OFFS 0u             // 102400*18*4 = 7372800
#define WS_WA   7372800u       // 9*128*128*2 = 294912  bf16 [k][o][c]
#define WS_GSUM 7667712u       // 512
#define WS_GSQ  7668224u       // 512
#define WS_WP   7668736u       // 6912*4 = 27648  packed offs weights [c][tap][6]
#define WS_XT   7696384u       // 102400*128*2 = 26214400 (bf16 NHWC)
#define WS_RAW  33910784u      // 4*128*25600*4 = 52428800

// --------------------------------------------------------------------------
// Kernel W: w_dcn [o][c][k] -> wA bf16 [k][o][c]; also pack tm/tr weights
// into wP[c][tap][6] for wave-uniform scalar streaming in offs_kernel.
__global__ void wtrans_kernel(const float* __restrict__ w_dcn,
                              const float* __restrict__ w_tm,
                              const float* __restrict__ w_tr,
                              unsigned short* __restrict__ wA,
                              float* __restrict__ wP) {
    int idx = blockIdx.x * 256 + threadIdx.x;
    if (idx < 6912) {
        int j = idx % 6;
        int rest = idx / 6;
        int tap = rest % 9;
        int c = rest / 9;
        float v = (j < 4) ? w_tm[(j * 128 + c) * 9 + tap]
                          : w_tr[((j - 4) * 128 + c) * 9 + tap];
        wP[(c * 9 + tap) * 6 + j] = v;
    }
    if (idx >= 9 * 128 * 128) return;
    int k = idx >> 14;
    int o = (idx >> 7) & 127;
    int c = idx & 127;
    wA[idx] = f2bf(w_dcn[(o * 128 + c) * 9 + k]);
}

// --------------------------------------------------------------------------
// Kernel X: NCHW fp32 -> NHWC bf16 transpose via LDS tile
__global__ void __launch_bounds__(256) xpose_kernel(
    const float* __restrict__ x, unsigned short* __restrict__ xT) {
    __shared__ float L[128 * 65];
    int b = blockIdx.x;
    int n = b / 400;
    int px0 = (b - n * 400) * 64;
    int t = threadIdx.x;
    const float* xn = x + (size_t)n * Cc * HW + px0;
#pragma unroll
    for (int i = 0; i < 32; ++i) {
        int idx = i * 256 + t;
        int ch = idx >> 6;
        int pxl = idx & 63;
        L[ch * 65 + pxl] = xn[(size_t)ch * HW + pxl];
    }
    __syncthreads();
    unsigned short* dst = xT + ((size_t)n * HW + px0) * 128;
#pragma unroll
    for (int j = 0; j < 16; ++j) {
        int idx = j * 256 + t;
        int pxl = idx >> 6;
        int cp = idx & 63;
        unsigned int u = (unsigned)f2bf(L[(2 * cp) * 65 + pxl]) |
                         ((unsigned)f2bf(L[(2 * cp + 1) * 65 + pxl]) << 16);
        *(unsigned int*)(dst + (size_t)pxl * 128 + cp * 2) = u;
    }
}

// --------------------------------------------------------------------------
// Kernel A: fused tm/tr 3x3 convs -> per-pixel (py,px) x 9 taps.
// Weights streamed from wP via wave-uniform scalar loads (s_load broadcast),
// no LDS, no barriers. 128-thread blocks for grid coverage.
__global__ void __launch_bounds__(128) offs_kernel(
    const float* __restrict__ x, const float* __restrict__ wP,
    const float* __restrict__ b_tm, const float* __restrict__ b_tr,
    float* __restrict__ offs) {
    int t = threadIdx.x;
    int p = blockIdx.x * 128 + t;
    int n = p / HW;
    int hw = p - n * HW;
    int h = hw / Ww;
    int w = hw - h * Ww;
    int addr[9];
    float msk[9];
#pragma unroll
    for (int tap = 0; tap < 9; ++tap) {
        int dy = tap / 3 - 1, dx = tap % 3 - 1;
        int yy = h + dy, xx = w + dx;
        bool v = (yy >= 0) && (yy < Hh) && (xx >= 0) && (xx < Ww);
        addr[tap] = v ? yy * Ww + xx : 0;
        msk[tap] = v ? 1.f : 0.f;
    }
    float a0 = 0, a1 = 0, a2 = 0, a3 = 0, a4 = 0, a5 = 0;
    const float* xn = x + n * Cc * HW;
    for (int c = 0; c < Cc; ++c) {
        const float* xc = xn + c * HW;
        const float* wc = wP + c * 54;          // uniform -> SGPR stream
#pragma unroll
        for (int tap = 0; tap < 9; ++tap) {
            float v = msk[tap] * xc[addr[tap]];
            a0 += v * wc[tap * 6 + 0];
            a1 += v * wc[tap * 6 + 1];
            a2 += v * wc[tap * 6 + 2];
            a3 += v * wc[tap * 6 + 3];
            a4 += v * wc[tap * 6 + 4];
            a5 += v * wc[tap * 6 + 5];
        }
    }
    a0 += b_tm[0]; a1 += b_tm[1]; a2 += b_tm[2]; a3 += b_tm[3];
    a4 += b_tr[0]; a5 += b_tr[1];
    float* op = offs + (size_t)p * 18;
#pragma unroll
    for (int k = 0; k < 9; ++k) {
        float r0 = (float)(k / 3) - 1.f;
        float r1 = (float)(k % 3) - 1.f;
        op[k * 2 + 0] = (float)h + a0 * r0 + a1 * r1 + a4;
        op[k * 2 + 1] = (float)w + a2 * r0 + a3 * r1 + a5;
    }
}

// --------------------------------------------------------------------------
// Kernel D: FUSED deformable conv. XCD-swizzled blocks: each XCD's 100
// blocks cover one contiguous 12800-px slice -> ~3.3MB xT working set
// fits the 4MiB per-XCD L2 (was: 545MB HBM/fabric fetch, 58% L2 miss).
__global__ void __launch_bounds__(256, 3) dcn2_kernel(
    const unsigned short* __restrict__ xT, const float* __restrict__ offs,
    const unsigned short* __restrict__ wA, float* __restrict__ raw,
    float* __restrict__ gsum, float* __restrict__ gsq) {
    __shared__ __align__(16) unsigned short Bt[128 * 128];   // 32 KB
    int t = threadIdx.x;
    int lane = t & 63;
    int wid = t >> 6;
    int wm = wid & 1, wn = wid >> 1;
    int quad = lane >> 4, l15 = lane & 15;

    int bid = blockIdx.x;
    int blk = (bid & 7) * 100 + (bid >> 3);   // XCD-contiguous px slices
    int px0 = blk * 128;
    int n = px0 / HW;
    int hw0 = px0 - n * HW;
    int pl = t >> 1;                       // staging pixel 0..127
    int hf = t & 1;                        // staging channel half (64 ch)
    const unsigned short* xb = xT + (size_t)n * HW * 128;
    const float* op = offs + (size_t)(px0 + pl) * 18;
    const char* Ag = (const char*)wA;

    // preload all 9 taps' coords (off the per-tap critical path)
    float o18[18];
#pragma unroll
    for (int i = 0; i < 9; ++i)
        *(float2*)&o18[2 * i] = *(const float2*)(op + 2 * i);

    f32x4 acc[4][4];
#pragma unroll
    for (int i = 0; i < 4; ++i)
#pragma unroll
        for (int j = 0; j < 4; ++j) acc[i][j] = (f32x4)0.f;

    for (int k = 0; k < 9; ++k) {
        float py = o18[2 * k + 0];
        float px = o18[2 * k + 1];
        float y0f = floorf(py), x0f = floorf(px);
        float fy = py - y0f, fx = px - x0f;
        int y0 = (int)y0f, xi0 = (int)x0f;
        int y1 = y0 + 1, xi1 = xi0 + 1;
        float w00 = (1.f - fy) * (1.f - fx), w01 = (1.f - fy) * fx;
        float w10 = fy * (1.f - fx), w11 = fy * fx;
        bool vy0 = (unsigned)y0 < (unsigned)Hh, vy1 = (unsigned)y1 < (unsigned)Hh;
        bool vx0 = (unsigned)xi0 < (unsigned)Ww, vx1 = (unsigned)xi1 < (unsigned)Ww;
        w00 = (vy0 && vx0) ? w00 : 0.f;
        w01 = (vy0 && vx1) ? w01 : 0.f;
        w10 = (vy1 && vx0) ? w10 : 0.f;
        w11 = (vy1 && vx1) ? w11 : 0.f;
        int cy0 = vy0 ? y0 : 0, cy1 = vy1 ? y1 : 0;
        int cx0 = vx0 ? xi0 : 0, cx1 = vx1 ? xi1 : 0;
        const unsigned short* c00 = xb + (size_t)(cy0 * Ww + cx0) * 128;
        const unsigned short* c01 = xb + (size_t)(cy0 * Ww + cx1) * 128;
        const unsigned short* c10 = xb + (size_t)(cy1 * Ww + cx0) * 128;
        const unsigned short* c11 = xb + (size_t)(cy1 * Ww + cx1) * 128;

        __syncthreads();                   // prev tap's MFMA reads done
#pragma unroll
        for (int uu = 0; uu < 4; ++uu) {
            int ch0 = hf * 64 + uu * 16;   // 16 channels per chunk
            u32x4 A0 = *(const u32x4*)(c00 + ch0);
            u32x4 A1 = *(const u32x4*)(c00 + ch0 + 8);
            u32x4 B0 = *(const u32x4*)(c01 + ch0);
            u32x4 B1 = *(const u32x4*)(c01 + ch0 + 8);
            u32x4 C0 = *(const u32x4*)(c10 + ch0);
            u32x4 C1 = *(const u32x4*)(c10 + ch0 + 8);
            u32x4 D0 = *(const u32x4*)(c11 + ch0);
            u32x4 D1 = *(const u32x4*)(c11 + ch0 + 8);
            u32x4 r0, r1;
#pragma unroll
            for (int e = 0; e < 4; ++e) {
                float lo = w00 * bflo(A0[e]) + w01 * bflo(B0[e]) +
                           w10 * bflo(C0[e]) + w11 * bflo(D0[e]);
                float hi = w00 * bfhi(A0[e]) + w01 * bfhi(B0[e]) +
                           w10 * bfhi(C0[e]) + w11 * bfhi(D0[e]);
                r0[e] = (unsigned)f2bf(lo) | ((unsigned)f2bf(hi) << 16);
                float lo1 = w00 * bflo(A1[e]) + w01 * bflo(B1[e]) +
                            w10 * bflo(C1[e]) + w11 * bflo(D1[e]);
                float hi1 = w00 * bfhi(A1[e]) + w01 * bfhi(B1[e]) +
                            w10 * bfhi(C1[e]) + w11 * bfhi(D1[e]);
                r1[e] = (unsigned)f2bf(lo1) | ((unsigned)f2bf(hi1) << 16);
            }
            int u = ch0 >> 3;              // 16B-unit index (0..15)
            *(u32x4*)&Bt[pl * 128 + (((u    ) ^ (pl & 15)) << 3)] = r0;
            *(u32x4*)&Bt[pl * 128 + (((u + 1) ^ (pl & 15)) << 3)] = r1;
        }
        __syncthreads();

#pragma unroll
        for (int q = 0; q < 4; ++q) {
            short8 a[4], b[4];
#pragma unroll
            for (int i = 0; i < 4; ++i)
                a[i] = *(const short8*)(Ag +
                        ((size_t)(k * 128 + wm * 64 + i * 16 + l15) << 8) +
                        q * 64 + quad * 16);
#pragma unroll
            for (int j = 0; j < 4; ++j) {
                int row = wn * 64 + j * 16 + l15;
                int ur = (q * 4 + quad) ^ (row & 15);
                b[j] = *(const short8*)&Bt[row * 128 + ur * 8];
            }
#pragma unroll
            for (int i = 0; i < 4; ++i)
#pragma unroll
                for (int j = 0; j < 4; ++j)
                    acc[i][j] = __builtin_amdgcn_mfma_f32_16x16x32_bf16(
                        a[i], b[j], acc[i][j], 0, 0, 0);
        }
    }

    // ---- epilogue: raw out (D[m=o][n=px]) + group sums ----
    size_t rbase = ((size_t)n * Cc) * HW + hw0;
#pragma unroll
    for (int i = 0; i < 4; ++i) {
        float s_i = 0.f, q_i = 0.f;
#pragma unroll
        for (int j = 0; j < 4; ++j) {
            int pxl = wn * 64 + j * 16 + l15;
#pragma unroll
            for (int r = 0; r < 4; ++r) {
                int o = wm * 64 + i * 16 + quad * 4 + r;
                float v = acc[i][j][r];
                raw[rbase + (size_t)o * HW + pxl] = v;
                s_i += v;
                q_i += v * v;
            }
        }
#pragma unroll
        for (int m = 1; m < 16; m <<= 1) {
            s_i += __shfl_xor(s_i, m);
            q_i += __shfl_xor(q_i, m);
        }
        if (l15 == 0) {
            int g = wm * 16 + i * 4 + quad;
            atomicAdd(&gsum[n * 32 + g], s_i);
            atomicAdd(&gsq[n * 32 + g], q_i);
        }
    }
}

// --------------------------------------------------------------------------
// Kernel C: GroupNorm finalize + residual + ReLU (float4)
__global__ void __launch_bounds__(256) finish_kernel(
    const float* __restrict__ raw, const float* __restrict__ x,
    const float* __restrict__ gsum, const float* __restrict__ gsq,
    const float* __restrict__ gamma, const float* __restrict__ beta,
    float* __restrict__ out) {
    int i = blockIdx.x * 256 + threadIdx.x;
    int e = i * 4;
    int n = e / (Cc * HW);
    int rem = e - n * (Cc * HW);
    int c = rem / HW;
    int g = c >> 2;
    const float inv = 1.f / 102400.f;
    float mu = gsum[n * 32 + g] * inv;
    float var = gsq[n * 32 + g] * inv - mu * mu;
    float rs = rsqrtf(var + 1e-5f);
    float sc = gamma[c] * rs;
    float sh = beta[c] - mu * sc;
    float4 v = *(const float4*)&raw[e];
    float4 xv = *(const float4*)&x[e];
    float4 r;
    r.x = fmaxf(v.x * sc + sh + xv.x, 0.f);
    r.y = fmaxf(v.y * sc + sh + xv.y, 0.f);
    r.z = fmaxf(v.z * sc + sh + xv.z, 0.f);
    r.w = fmaxf(v.w * sc + sh + xv.w, 0.f);
    *(float4*)&out[e] = r;
}

// --------------------------------------------------------------------------
extern "C" void kernel_launch(void* const* d_in, const int* in_sizes, int n_in,
                              void* d_out, int out_size, void* d_ws, size_t ws_size,
                              hipStream_t stream) {
    const float* x      = (const float*)d_in[0];
    const float* w_tm   = (const float*)d_in[1];
    const float* b_tm   = (const float*)d_in[2];
    const float* w_tr   = (const float*)d_in[3];
    const float* b_tr   = (const float*)d_in[4];
    const float* w_dcn  = (const float*)d_in[5];
    const float* gamma  = (const float*)d_in[6];
    const float* beta   = (const float*)d_in[7];
    char* ws = (char*)d_ws;
    float*          offs = (float*)(ws + WS_OFFS);
    unsigned short* wA   = (unsigned short*)(ws + WS_WA);
    float*          gsum = (float*)(ws + WS_GSUM);
    float*          gsq  = (float*)(ws + WS_GSQ);
    float*          wP   = (float*)(ws + WS_WP);
    unsigned short* xT   = (unsigned short*)(ws + WS_XT);
    float*          raw  = (float*)(ws + WS_RAW);
    float* out = (float*)d_out;

    (void)hipMemsetAsync(gsum, 0, 1024, stream);   // gsum + gsq
    wtrans_kernel<<<576, 256, 0, stream>>>(w_dcn, w_tm, w_tr, wA, wP);
    xpose_kernel<<<1600, 256, 0, stream>>>(x, xT);
    offs_kernel<<<800, 128, 0, stream>>>(x, wP, b_tm, b_tr, offs);
    dcn2_kernel<<<800, 256, 0, stream>>>(xT, offs, wA, raw, gsum, gsq);
    finish_kernel<<<12800, 256, 0, stream>>>(raw, x, gsum, gsq, gamma, beta, out);
}

// Round 7
// 358.525 us; speedup vs baseline: 4.7760x; 1.1530x over previous
//
#include <hip/hip_runtime.h>
#include <hip/hip_fp16.h>
#include <math.h>

#define Hh 160
#define Ww 160
#define Cc 128
#define HW 25600
#define NPIX 102400   // N*H*W, N=4

typedef __attribute__((ext_vector_type(8))) _Float16 half8;
typedef __attribute__((ext_vector_type(4))) float f32x4;
typedef __attribute__((ext_vector_type(4))) unsigned int u32x4;

union h2u { __half2 h; unsigned int u; };

// ws byte layout (all 16B aligned)
#define WS_OFFS 0u             // 9*102400*2*4 = 7372800  [k][p][2] fp32
#define WS_WA   7372800u       // 9*128*128*2 = 294912  fp16 [k][o][c]
#define WS_GSUM 7667712u       // 512
#define WS_GSQ  7668224u       // 512
#define WS_XT   7668736u       // 102400*128*2 = 26214400 (fp16 NHWC)
#define WS_RAW  33883136u      // 4*128*25600*4 = 52428800

// --------------------------------------------------------------------------
// Kernel W: w_dcn [o][c][k] -> wA fp16 [k][o][c]
__global__ void wtrans_kernel(const float* __restrict__ w_dcn,
                              unsigned short* __restrict__ wA) {
    int idx = blockIdx.x * 256 + threadIdx.x;
    if (idx >= 9 * 128 * 128) return;
    int k = idx >> 14;
    int o = (idx >> 7) & 127;
    int c = idx & 127;
    wA[idx] = __half_as_ushort(__float2half(w_dcn[(o * 128 + c) * 9 + k]));
}

// --------------------------------------------------------------------------
// Kernel X: NCHW fp32 -> NHWC fp16 transpose via LDS tile
__global__ void __launch_bounds__(256) xpose_kernel(
    const float* __restrict__ x, unsigned short* __restrict__ xT) {
    __shared__ float L[128 * 65];
    int b = blockIdx.x;
    int n = b / 400;
    int px0 = (b - n * 400) * 64;
    int t = threadIdx.x;
    const float* xn = x + (size_t)n * Cc * HW + px0;
#pragma unroll
    for (int i = 0; i < 32; ++i) {
        int idx = i * 256 + t;
        int ch = idx >> 6;
        int pxl = idx & 63;
        L[ch * 65 + pxl] = xn[(size_t)ch * HW + pxl];
    }
    __syncthreads();
    unsigned short* dst = xT + ((size_t)n * HW + px0) * 128;
#pragma unroll
    for (int j = 0; j < 16; ++j) {
        int idx = j * 256 + t;
        int pxl = idx >> 6;
        int cp = idx & 63;
        h2u cv;
        cv.h = __floats2half2_rn(L[(2 * cp) * 65 + pxl],
                                 L[(2 * cp + 1) * 65 + pxl]);
        *(unsigned int*)(dst + (size_t)pxl * 128 + cp * 2) = cv.u;
    }
}

// --------------------------------------------------------------------------
// Kernel A: fused tm/tr 3x3 convs -> offs2[k][p][2] (py,px per tap)
__global__ void __launch_bounds__(256) offs_kernel(
    const float* __restrict__ x, const float* __restrict__ w_tm,
    const float* __restrict__ b_tm, const float* __restrict__ w_tr,
    const float* __restrict__ b_tr, float* __restrict__ offs2) {
    __shared__ float wt[128 * 9 * 8];
    int t = threadIdx.x;
    for (int idx = t; idx < 6912; idx += 256) {
        int j = idx % 6;
        int rest = idx / 6;
        int tap = rest % 9;
        int c = rest / 9;
        float v = (j < 4) ? w_tm[(j * 128 + c) * 9 + tap]
                          : w_tr[((j - 4) * 128 + c) * 9 + tap];
        wt[rest * 8 + j] = v;
    }
    __syncthreads();
    int bid = blockIdx.x;                  // 400 blocks, XCD-contiguous slices
    int blk = (bid & 7) * 50 + (bid >> 3);
    int p = blk * 256 + t;
    int n = p / HW;
    int hw = p - n * HW;
    int h = hw / Ww;
    int w = hw - h * Ww;
    int addr[9];
    float msk[9];
#pragma unroll
    for (int tap = 0; tap < 9; ++tap) {
        int dy = tap / 3 - 1, dx = tap % 3 - 1;
        int yy = h + dy, xx = w + dx;
        bool v = (yy >= 0) && (yy < Hh) && (xx >= 0) && (xx < Ww);
        addr[tap] = v ? yy * Ww + xx : 0;
        msk[tap] = v ? 1.f : 0.f;
    }
    float a0 = 0, a1 = 0, a2 = 0, a3 = 0, a4 = 0, a5 = 0;
    const float* xn = x + n * Cc * HW;
#pragma unroll 2
    for (int c = 0; c < Cc; ++c) {
        const float* xc = xn + c * HW;
#pragma unroll
        for (int tap = 0; tap < 9; ++tap) {
            float v = msk[tap] * xc[addr[tap]];
            const float* wp = &wt[(c * 9 + tap) * 8];
            float4 w4 = *(const float4*)wp;
            float2 w2 = *(const float2*)(wp + 4);
            a0 += v * w4.x; a1 += v * w4.y; a2 += v * w4.z; a3 += v * w4.w;
            a4 += v * w2.x; a5 += v * w2.y;
        }
    }
    a0 += b_tm[0]; a1 += b_tm[1]; a2 += b_tm[2]; a3 += b_tm[3];
    a4 += b_tr[0]; a5 += b_tr[1];
#pragma unroll
    for (int k = 0; k < 9; ++k) {
        float r0 = (float)(k / 3) - 1.f;
        float r1 = (float)(k % 3) - 1.f;
        float2 st;
        st.x = (float)h + a0 * r0 + a1 * r1 + a4;
        st.y = (float)w + a2 * r0 + a3 * r1 + a5;
        *(float2*)(offs2 + ((size_t)k * NPIX + p) * 2) = st;
    }
}

// --------------------------------------------------------------------------
// Kernel D: FUSED deformable conv (fp16). Block = 128px x 128o, XCD-swizzled.
// Staging: 4 px per wave-round, 16 lanes per 256B corner cell -> every gather
// is 4-line coalesced; corners combined in-register with v_pk_fma_f16 (no
// shuffles, no unpack). MFMA: f32_16x16x32_f16, A-frags direct from global.
__global__ void __launch_bounds__(256, 3) dcn2_kernel(
    const unsigned short* __restrict__ xT, const float* __restrict__ offs2,
    const unsigned short* __restrict__ wA, float* __restrict__ raw,
    float* __restrict__ gsum, float* __restrict__ gsq) {
    __shared__ __align__(16) unsigned short Bt[128 * 128];   // 32 KB
    int t = threadIdx.x;
    int lane = t & 63;
    int wid = t >> 6;
    int wm = wid & 1, wn = wid >> 1;
    int quad = lane >> 4, l15 = lane & 15;
    int sub = lane >> 4;                   // staging: px sub-index 0..3
    int s = lane & 15;                     // staging: 16B segment 0..15

    int bid = blockIdx.x;
    int blk = (bid & 7) * 100 + (bid >> 3);   // XCD-contiguous px slices
    int px0 = blk * 128;
    int n = px0 / HW;
    int hw0 = px0 - n * HW;
    const unsigned short* xb = xT + (size_t)n * HW * 128;
    const char* Ag = (const char*)wA;

    f32x4 acc[4][4];
#pragma unroll
    for (int i = 0; i < 4; ++i)
#pragma unroll
        for (int j = 0; j < 4; ++j) acc[i][j] = (f32x4)0.f;

    for (int k = 0; k < 9; ++k) {
        __syncthreads();                   // prev tap's MFMA reads done
#pragma unroll 2
        for (int r = 0; r < 8; ++r) {
            int p = wid * 32 + r * 4 + sub;
            const float2 pc = *(const float2*)(offs2 +
                                ((size_t)k * NPIX + px0 + p) * 2);
            float py = pc.x, pxx = pc.y;
            float y0f = floorf(py), x0f = floorf(pxx);
            float fy = py - y0f, fx = pxx - x0f;
            int y0 = (int)y0f, xi0 = (int)x0f;
            int y1 = y0 + 1, xi1 = xi0 + 1;
            float w00 = (1.f - fy) * (1.f - fx), w01 = (1.f - fy) * fx;
            float w10 = fy * (1.f - fx), w11 = fy * fx;
            bool vy0 = (unsigned)y0 < (unsigned)Hh;
            bool vy1 = (unsigned)y1 < (unsigned)Hh;
            bool vx0 = (unsigned)xi0 < (unsigned)Ww;
            bool vx1 = (unsigned)xi1 < (unsigned)Ww;
            w00 = (vy0 && vx0) ? w00 : 0.f;
            w01 = (vy0 && vx1) ? w01 : 0.f;
            w10 = (vy1 && vx0) ? w10 : 0.f;
            w11 = (vy1 && vx1) ? w11 : 0.f;
            int cy0 = vy0 ? y0 : 0, cy1 = vy1 ? y1 : 0;
            int cx0 = vx0 ? xi0 : 0, cx1 = vx1 ? xi1 : 0;
            int sb = s << 3;
            u32x4 v00 = *(const u32x4*)(xb + ((size_t)(cy0 * Ww + cx0) << 7) + sb);
            u32x4 v01 = *(const u32x4*)(xb + ((size_t)(cy0 * Ww + cx1) << 7) + sb);
            u32x4 v10 = *(const u32x4*)(xb + ((size_t)(cy1 * Ww + cx0) << 7) + sb);
            u32x4 v11 = *(const u32x4*)(xb + ((size_t)(cy1 * Ww + cx1) << 7) + sb);
            __half2 W00 = __float2half2_rn(w00);
            __half2 W01 = __float2half2_rn(w01);
            __half2 W10 = __float2half2_rn(w10);
            __half2 W11 = __float2half2_rn(w11);
            u32x4 outv;
#pragma unroll
            for (int e = 0; e < 4; ++e) {
                h2u a, b, c, d, o;
                a.u = v00[e]; b.u = v01[e]; c.u = v10[e]; d.u = v11[e];
                __half2 acc2 = __hmul2(W11, d.h);
                acc2 = __hfma2(W10, c.h, acc2);
                acc2 = __hfma2(W01, b.h, acc2);
                acc2 = __hfma2(W00, a.h, acc2);
                o.h = acc2;
                outv[e] = o.u;
            }
            *(u32x4*)&Bt[p * 128 + ((s ^ (p & 15)) << 3)] = outv;
        }
        __syncthreads();

#pragma unroll
        for (int q = 0; q < 4; ++q) {
            half8 a[4], b[4];
#pragma unroll
            for (int i = 0; i < 4; ++i)
                a[i] = *(const half8*)(Ag +
                        ((size_t)(k * 128 + wm * 64 + i * 16 + l15) << 8) +
                        q * 64 + quad * 16);
#pragma unroll
            for (int j = 0; j < 4; ++j) {
                int row = wn * 64 + j * 16 + l15;
                int ur = (q * 4 + quad) ^ (row & 15);
                b[j] = *(const half8*)&Bt[row * 128 + ur * 8];
            }
#pragma unroll
            for (int i = 0; i < 4; ++i)
#pragma unroll
                for (int j = 0; j < 4; ++j)
                    acc[i][j] = __builtin_amdgcn_mfma_f32_16x16x32_f16(
                        a[i], b[j], acc[i][j], 0, 0, 0);
        }
    }

    // ---- epilogue: raw out (D[m=o][n=px]) + group sums ----
    size_t rbase = ((size_t)n * Cc) * HW + hw0;
#pragma unroll
    for (int i = 0; i < 4; ++i) {
        float s_i = 0.f, q_i = 0.f;
#pragma unroll
        for (int j = 0; j < 4; ++j) {
            int pxl = wn * 64 + j * 16 + l15;
#pragma unroll
            for (int rr = 0; rr < 4; ++rr) {
                int o = wm * 64 + i * 16 + quad * 4 + rr;
                float v = acc[i][j][rr];
                raw[rbase + (size_t)o * HW + pxl] = v;
                s_i += v;
                q_i += v * v;
            }
        }
#pragma unroll
        for (int m = 1; m < 16; m <<= 1) {
            s_i += __shfl_xor(s_i, m);
            q_i += __shfl_xor(q_i, m);
        }
        if (l15 == 0) {
            int g = wm * 16 + i * 4 + quad;
            atomicAdd(&gsum[n * 32 + g], s_i);
            atomicAdd(&gsq[n * 32 + g], q_i);
        }
    }
}

// --------------------------------------------------------------------------
// Kernel C: GroupNorm finalize + residual + ReLU (float4)
__global__ void __launch_bounds__(256) finish_kernel(
    const float* __restrict__ raw, const float* __restrict__ x,
    const float* __restrict__ gsum, const float* __restrict__ gsq,
    const float* __restrict__ gamma, const float* __restrict__ beta,
    float* __restrict__ out) {
    int i = blockIdx.x * 256 + threadIdx.x;
    int e = i * 4;
    int n = e / (Cc * HW);
    int rem = e - n * (Cc * HW);
    int c = rem / HW;
    int g = c >> 2;
    const float inv = 1.f / 102400.f;
    float mu = gsum[n * 32 + g] * inv;
    float var = gsq[n * 32 + g] * inv - mu * mu;
    float rs = rsqrtf(var + 1e-5f);
    float sc = gamma[c] * rs;
    float sh = beta[c] - mu * sc;
    float4 v = *(const float4*)&raw[e];
    float4 xv = *(const float4*)&x[e];
    float4 r;
    r.x = fmaxf(v.x * sc + sh + xv.x, 0.f);
    r.y = fmaxf(v.y * sc + sh + xv.y, 0.f);
    r.z = fmaxf(v.z * sc + sh + xv.z, 0.f);
    r.w = fmaxf(v.w * sc + sh + xv.w, 0.f);
    *(float4*)&out[e] = r;
}

// --------------------------------------------------------------------------
extern "C" void kernel_launch(void* const* d_in, const int* in_sizes, int n_in,
                              void* d_out, int out_size, void* d_ws, size_t ws_size,
                              hipStream_t stream) {
    const float* x      = (const float*)d_in[0];
    const float* w_tm   = (const float*)d_in[1];
    const float* b_tm   = (const float*)d_in[2];
    const float* w_tr   = (const float*)d_in[3];
    const float* b_tr   = (const float*)d_in[4];
    const float* w_dcn  = (const float*)d_in[5];
    const float* gamma  = (const float*)d_in[6];
    const float* beta   = (const float*)d_in[7];
    char* ws = (char*)d_ws;
    float*          offs2 = (float*)(ws + WS_OFFS);
    unsigned short* wA    = (unsigned short*)(ws + WS_WA);
    float*          gsum  = (float*)(ws + WS_GSUM);
    float*          gsq   = (float*)(ws + WS_GSQ);
    unsigned short* xT    = (unsigned short*)(ws + WS_XT);
    float*          raw   = (float*)(ws + WS_RAW);
    float* out = (float*)d_out;

    (void)hipMemsetAsync(gsum, 0, 1024, stream);   // gsum + gsq
    wtrans_kernel<<<576, 256, 0, stream>>>(w_dcn, wA);
    xpose_kernel<<<1600, 256, 0, stream>>>(x, xT);
    offs_kernel<<<400, 256, 0, stream>>>(x, w_tm, b_tm, w_tr, b_tr, offs2);
    dcn2_kernel<<<800, 256, 0, stream>>>(xT, offs2, wA, raw, gsum, gsq);
    finish_kernel<<<12800, 256, 0, stream>>>(raw, x, gsum, gsq, gamma, beta, out);
}